// Round 18
// baseline (681.571 us; speedup 1.0000x reference)
//
#include <hip/hip_runtime.h>
#include <cmath>

#define TID ((int)threadIdx.x)

typedef __bf16 bf16_t;
typedef bf16_t bf16x8 __attribute__((ext_vector_type(8)));
typedef float floatx4 __attribute__((ext_vector_type(4)));

#define MFMA(a, b, c) __builtin_amdgcn_mfma_f32_16x16x32_bf16(a, b, c, 0, 0, 0)
// barrier #1 of a phase: buf ready (drain all but the N just-issued prefetch loads)
#define WAIT_BAR(N)  do { asm volatile("s_waitcnt vmcnt(" #N ")" ::: "memory"); \
                          __builtin_amdgcn_s_barrier(); \
                          __builtin_amdgcn_sched_barrier(0); } while (0)
// barrier #2 of a phase: this wave's ds_reads complete -> after barrier, buf may be overwritten
#define LGKM_BAR     do { asm volatile("s_waitcnt lgkmcnt(0)" ::: "memory"); \
                          __builtin_amdgcn_s_barrier(); \
                          __builtin_amdgcn_sched_barrier(0); } while (0)

constexpr int N_IN = 10000;
constexpr int XP   = 10001;   // x row pitch
constexpr int KPD  = 10240;   // padded K for W_down^T
constexpr int HH   = 512;
constexpr int TT   = 16;
constexpr int NB   = 512;
constexpr int MROW = 8192;    // NB*TT
constexpr int KSPLIT = 8;
constexpr int KCHUNK = 1280;  // KPD/KSPLIT
constexpr int KT_A = 20;      // KCHUNK/64

__device__ __forceinline__ float sigm(float x) { return 1.0f / (1.0f + expf(-x)); }

__device__ __forceinline__ void gload16(const void* g, void* lds) {
  __builtin_amdgcn_global_load_lds(
      (const __attribute__((address_space(1))) unsigned int*)g,
      (__attribute__((address_space(3))) unsigned int*)lds, 16, 0, 0);
}

// ---------- fused prep: blocks 0-159 -> W_down split/transpose; 160-335 -> W_cell split
__global__ __launch_bounds__(256)
void kPrep(const float* __restrict__ Wd, const float* __restrict__ Wc,
           bf16_t* __restrict__ Whi, bf16_t* __restrict__ Wlo,
           bf16_t* __restrict__ Wxh, bf16_t* __restrict__ Wxl,
           float* __restrict__ wN, bf16_t* __restrict__ Whh, bf16_t* __restrict__ Whl) {
  __shared__ float Ts[64][133];
  const int lane = TID & 63, w = TID >> 6;
  if (blockIdx.x < 160) {
    // ---- W_down (10000x128) -> WdT hi/lo bf16 [128][10240]
    const int k0 = blockIdx.x * 64;
    #pragma unroll
    for (int i = 0; i < 32; ++i) {
      int f = TID + 256 * i;
      int kk = f >> 7, c = f & 127;
      int k = k0 + kk;
      Ts[kk][c] = (k < N_IN) ? Wd[(size_t)k * 128 + c] : 0.0f;
    }
    __syncthreads();
    for (int pass = 0; pass < 32; ++pass) {
      int c = pass * 4 + w;
      float v = Ts[lane][c];
      bf16_t hi = (bf16_t)v;
      bf16_t lo = (bf16_t)(v - (float)hi);
      Whi[(size_t)c * KPD + k0 + lane] = hi;
      Wlo[(size_t)c * KPD + k0 + lane] = lo;
    }
  } else {
    // ---- W_cell (641x2048) -> WxT[2048][128], wN[2048], WhT[2048][512] (hi/lo)
    const int id = blockIdx.x - 160;           // 0..175 = 11 k-tiles x 16 c-tiles
    const int k0 = (id % 11) * 64;
    const int c0 = (id / 11) * 128;
    #pragma unroll
    for (int i = 0; i < 32; ++i) {
      int f = TID + 256 * i;
      int kk = f >> 7, cc = f & 127;
      int k = k0 + kk;
      Ts[kk][cc] = (k < 641) ? Wc[(size_t)k * 2048 + c0 + cc] : 0.0f;
    }
    __syncthreads();
    const int k = k0 + lane;
    for (int pass = 0; pass < 32; ++pass) {
      int cc = pass * 4 + w;
      int c = c0 + cc;
      float v = Ts[lane][cc];
      bf16_t hi = (bf16_t)v;
      bf16_t lo = (bf16_t)(v - (float)hi);
      if (k < 128) {
        Wxh[(size_t)c * 128 + k] = hi;
        Wxl[(size_t)c * 128 + k] = lo;
      } else if (k == 128) {
        wN[c] = v;
      } else if (k < 641) {
        Whh[(size_t)c * 512 + (k - 129)] = hi;
        Whl[(size_t)c * 512 + (k - 129)] = lo;
      }
    }
  }
}

// ---------- kernel A: parts[s] = x @ W_down chunk, bf16 3-pass MFMA (kt=64, 64KB dbuf)
// KSPLIT=8: 512 blocks (2/CU), 20 kt each, half the parts traffic of KSPLIT=16.
// 2-ahead x prefetch (3 reg buffers) + 1-ahead LDS stage, counted-vmcnt two-barrier phases.
__global__ __launch_bounds__(256, 2)
void kA_mfma(const float* __restrict__ x, const bf16_t* __restrict__ Whi,
             const bf16_t* __restrict__ Wlo, float* __restrict__ parts) {
  // chunk L = arr*1024 + col*8 + g (16B each); linear dest, pre-swizzled source
  __shared__ __align__(16) bf16_t Bt[2][2048 * 8];
  const int lane = TID & 63, w = TID >> 6;
  const int row0 = blockIdx.x * 128 + w * 32;
  const int kbase = blockIdx.y * KCHUNK;
  floatx4 acc[2][8] = {};

  auto STAGE = [&](int buf, int kt) {
    const int k0 = kbase + kt * 64;
    #pragma unroll
    for (int i = 0; i < 8; ++i) {
      int L = i * 256 + TID;
      int arr = L >> 10, col = (L >> 3) & 127, g = L & 7;
      int gs = g ^ (col & 7);
      const bf16_t* src = (arr ? Wlo : Whi) + (size_t)col * KPD + k0 + gs * 8;
      gload16(src, &Bt[buf][(size_t)L * 8]);
    }
  };
  // branchless: loads ALWAYS issued (clamped in-bounds addr), zeros selected after.
  auto LOADX = [&](float4 (&xb)[2][2][2], int kt) {
    const int k0 = kbase + kt * 64;
    #pragma unroll
    for (int rf = 0; rf < 2; ++rf) {
      const float* xp = x + (size_t)(row0 + rf * 16 + (lane & 15)) * XP;
      #pragma unroll
      for (int h = 0; h < 2; ++h) {
        int kk0 = k0 + h * 32 + (lane >> 4) * 8;
        int kc = (kk0 < N_IN) ? kk0 : (N_IN - 8);   // always valid, 8 floats in-bounds
        float4 v0 = *(const float4*)(xp + kc);
        float4 v1 = *(const float4*)(xp + kc + 4);
        if (kk0 >= N_IN) {
          v0 = make_float4(0.f, 0.f, 0.f, 0.f);
          v1 = make_float4(0.f, 0.f, 0.f, 0.f);
        }
        xb[rf][h][0] = v0;
        xb[rf][h][1] = v1;
      }
    }
  };
  auto COMPUTE = [&](int buf, const float4 (&xb)[2][2][2]) {
    #pragma unroll
    for (int h = 0; h < 2; ++h) {
      const int p = h * 4 + (lane >> 4);
      bf16x8 ahi[2], alo[2];
      #pragma unroll
      for (int rf = 0; rf < 2; ++rf) {
        float vv[8] = {xb[rf][h][0].x, xb[rf][h][0].y, xb[rf][h][0].z, xb[rf][h][0].w,
                       xb[rf][h][1].x, xb[rf][h][1].y, xb[rf][h][1].z, xb[rf][h][1].w};
        #pragma unroll
        for (int e = 0; e < 8; ++e) {
          bf16_t hi = (bf16_t)vv[e];
          ahi[rf][e] = hi;
          alo[rf][e] = (bf16_t)(vv[e] - (float)hi);
        }
      }
      #pragma unroll
      for (int cf = 0; cf < 8; ++cf) {
        const int col = cf * 16 + (lane & 15);
        const int g = p ^ (col & 7);
        bf16x8 bhi = *(const bf16x8*)&Bt[buf][(col * 8 + g) * 8];
        bf16x8 blo = *(const bf16x8*)&Bt[buf][(1024 + col * 8 + g) * 8];
        #pragma unroll
        for (int rf = 0; rf < 2; ++rf) {
          acc[rf][cf] = MFMA(ahi[rf], bhi, acc[rf][cf]);
          acc[rf][cf] = MFMA(ahi[rf], blo, acc[rf][cf]);
          acc[rf][cf] = MFMA(alo[rf], bhi, acc[rf][cf]);
        }
      }
    }
  };

  float4 xb0[2][2][2], xb1[2][2][2], xb2[2][2][2];
  STAGE(0, 0); LOADX(xb0, 0);
  STAGE(1, 1); LOADX(xb1, 1);
  LOADX(xb2, 2);
  #pragma unroll
  for (int kt = 0; kt < KT_A; ++kt) {
    if (kt <= KT_A - 3)      WAIT_BAR(24);
    else if (kt == KT_A - 2) WAIT_BAR(16);
    else                     WAIT_BAR(0);
    if (kt % 3 == 0)      COMPUTE(kt & 1, xb0);
    else if (kt % 3 == 1) COMPUTE(kt & 1, xb1);
    else                  COMPUTE(kt & 1, xb2);
    LGKM_BAR;
    if (kt + 2 < KT_A) STAGE(kt & 1, kt + 2);
    if (kt + 3 < KT_A) {
      if ((kt + 3) % 3 == 0)      LOADX(xb0, kt + 3);
      else if ((kt + 3) % 3 == 1) LOADX(xb1, kt + 3);
      else                        LOADX(xb2, kt + 3);
    }
  }

  float* dst = parts + (size_t)blockIdx.y * MROW * 128;
  #pragma unroll
  for (int rf = 0; rf < 2; ++rf)
    #pragma unroll
    for (int cf = 0; cf < 8; ++cf)
      #pragma unroll
      for (int r = 0; r < 4; ++r) {
        int row = row0 + rf * 16 + (lane >> 4) * 4 + r;
        int col = cf * 16 + (lane & 15);
        dst[(size_t)row * 128 + col] = acc[rf][cf][r];
      }
}

// ---------- reduce partials -> xa [8192][128] (row = b*16+t)
__global__ __launch_bounds__(256)
void kRed(const float* __restrict__ parts, float* __restrict__ xa) {
  size_t i4 = ((size_t)blockIdx.x * 256 + TID) * 4;
  float4 v = make_float4(0.f, 0.f, 0.f, 0.f);
  #pragma unroll
  for (int s = 0; s < KSPLIT; ++s) {
    float4 p = *(const float4*)&parts[(size_t)s * MROW * 128 + i4];
    v.x += p.x; v.y += p.y; v.z += p.z; v.w += p.w;
  }
  *(float4*)&xa[i4] = v;
}

// ---------- gx = xa @ Wx + bc + x[:,N]*wN, layout gx[row][j*4+g], row = b*16+t
// grid (64 row-tiles, 16 col-tiles), 512 thr / 8 waves (4 row x 2 col), wave 32x64
__global__ __launch_bounds__(512, 2)
void kGx(const float* __restrict__ xa, const float* __restrict__ x,
         const bf16_t* __restrict__ Wxh, const bf16_t* __restrict__ Wxl,
         const float* __restrict__ wN, const float* __restrict__ bc,
         float* __restrict__ gx) {
  __shared__ __align__(16) bf16_t Bt[4096 * 8];
  const int lane = TID & 63, w = TID >> 6;
  const int wr = w & 3, wc = w >> 2;
  const int rowbase = blockIdx.x * 128 + wr * 32;
  const int JB = blockIdx.y * 32;
  floatx4 acc[2][4] = {};

  #pragma unroll
  for (int i = 0; i < 8; ++i) {
    int L = i * 512 + TID;
    int arr = L >> 11, ce = (L >> 4) & 127, g = L & 15;
    int gs = g ^ (ce & 15);
    int c_src = (ce & 3) * 512 + JB + (ce >> 2);
    const bf16_t* src = (arr ? Wxl : Wxh) + (size_t)c_src * 128 + gs * 8;
    gload16(src, &Bt[(size_t)L * 8]);
  }
  float4 xb[2][2][2][2];  // [kt][rf][h][half]
  #pragma unroll
  for (int kt = 0; kt < 2; ++kt)
    #pragma unroll
    for (int rf = 0; rf < 2; ++rf) {
      const float* ap = xa + (size_t)(rowbase + rf * 16 + (lane & 15)) * 128;
      #pragma unroll
      for (int h = 0; h < 2; ++h) {
        int kk0 = kt * 64 + h * 32 + (lane >> 4) * 8;
        xb[kt][rf][h][0] = *(const float4*)(ap + kk0);
        xb[kt][rf][h][1] = *(const float4*)(ap + kk0 + 4);
      }
    }
  __syncthreads();
  #pragma unroll
  for (int kt = 0; kt < 2; ++kt) {
    #pragma unroll
    for (int h = 0; h < 2; ++h) {
      const int p = kt * 8 + h * 4 + (lane >> 4);
      bf16x8 ahi[2], alo[2];
      #pragma unroll
      for (int rf = 0; rf < 2; ++rf) {
        float vv[8] = {xb[kt][rf][h][0].x, xb[kt][rf][h][0].y, xb[kt][rf][h][0].z, xb[kt][rf][h][0].w,
                       xb[kt][rf][h][1].x, xb[kt][rf][h][1].y, xb[kt][rf][h][1].z, xb[kt][rf][h][1].w};
        #pragma unroll
        for (int e = 0; e < 8; ++e) {
          bf16_t hi = (bf16_t)vv[e];
          ahi[rf][e] = hi;
          alo[rf][e] = (bf16_t)(vv[e] - (float)hi);
        }
      }
      #pragma unroll
      for (int cf = 0; cf < 4; ++cf) {
        const int ce = wc * 64 + cf * 16 + (lane & 15);
        const int g = p ^ (ce & 15);
        bf16x8 bhi = *(const bf16x8*)&Bt[(ce * 16 + g) * 8];
        bf16x8 blo = *(const bf16x8*)&Bt[(2048 + ce * 16 + g) * 8];
        #pragma unroll
        for (int rf = 0; rf < 2; ++rf) {
          acc[rf][cf] = MFMA(ahi[rf], bhi, acc[rf][cf]);
          acc[rf][cf] = MFMA(ahi[rf], blo, acc[rf][cf]);
          acc[rf][cf] = MFMA(alo[rf], bhi, acc[rf][cf]);
        }
      }
    }
  }
  #pragma unroll
  for (int rf = 0; rf < 2; ++rf)
    #pragma unroll
    for (int cf = 0; cf < 4; ++cf) {
      const int ce = wc * 64 + cf * 16 + (lane & 15);
      const int n = blockIdx.y * 128 + ce;
      const int c_src = (ce & 3) * 512 + JB + (ce >> 2);
      const float bias = bc[c_src];
      const float wn = wN[c_src];
      #pragma unroll
      for (int r = 0; r < 4; ++r) {
        int row = rowbase + rf * 16 + (lane >> 4) * 4 + r;
        float xwv = x[(size_t)row * XP + N_IN];
        gx[(size_t)row * 2048 + n] = acc[rf][cf][r] + bias + xwv * wn;
      }
    }
}

// ---------- one LSTM step: gates = h @ WhT + gx; pointwise; h out as bf16 hi/lo.
// When final: skip h/c stores, fused output projection via 16-lane reduce + atomicAdd.
// grid (32,16), 128 thr / 2 waves; two-barrier counted-vmcnt phases (12 in-flight).
__global__ __launch_bounds__(128, 2)
void kStepH(const bf16_t* __restrict__ hhi_in, const bf16_t* __restrict__ hlo_in,
            const bf16_t* __restrict__ Whh, const bf16_t* __restrict__ Whl,
            const float* __restrict__ gx, const float* __restrict__ c_in,
            bf16_t* __restrict__ hhi_out, bf16_t* __restrict__ hlo_out,
            float* __restrict__ c_out, const float* __restrict__ Wo,
            const float* __restrict__ bo, float* __restrict__ out,
            int t, int has_h, int final_step) {
  __shared__ __align__(16) bf16_t Bt[2][1024 * 8];  // L = arr*512 + ce*8 + g
  const int lane = TID & 63, w = TID >> 6;
  const int j0 = blockIdx.x * 16;
  const int brow0 = blockIdx.y * 32 + w * 16;
  floatx4 acc[4] = {};

  auto STAGE = [&](int buf, int kt) {
    const int k0 = kt * 64;
    #pragma unroll
    for (int i = 0; i < 8; ++i) {
      int L = i * 128 + TID;
      int arr = L >> 9, ce = (L >> 3) & 63, g = L & 7;
      int gs = g ^ (ce & 7);
      int c_src = (ce >> 4) * 512 + j0 + (ce & 15);
      const bf16_t* src = (arr ? Whl : Whh) + (size_t)c_src * 512 + k0 + gs * 8;
      gload16(src, &Bt[buf][(size_t)L * 8]);
    }
  };
  auto LOADA = [&](bf16x8 (&ar)[2][2], int kt) {
    const int b = brow0 + (lane & 15);
    #pragma unroll
    for (int h = 0; h < 2; ++h) {
      const int kk0 = kt * 64 + h * 32 + (lane >> 4) * 8;
      ar[h][0] = *(const bf16x8*)&hhi_in[(size_t)b * HH + kk0];
      ar[h][1] = *(const bf16x8*)&hlo_in[(size_t)b * HH + kk0];
    }
  };
  auto COMPUTE = [&](int buf, const bf16x8 (&ar)[2][2]) {
    #pragma unroll
    for (int h = 0; h < 2; ++h) {
      const int p = h * 4 + (lane >> 4);
      #pragma unroll
      for (int cf = 0; cf < 4; ++cf) {
        const int ce = cf * 16 + (lane & 15);
        const int g = p ^ (ce & 7);
        bf16x8 bhi = *(const bf16x8*)&Bt[buf][(ce * 8 + g) * 8];
        bf16x8 blo = *(const bf16x8*)&Bt[buf][(512 + ce * 8 + g) * 8];
        acc[cf] = MFMA(ar[h][0], bhi, acc[cf]);
        acc[cf] = MFMA(ar[h][0], blo, acc[cf]);
        acc[cf] = MFMA(ar[h][1], bhi, acc[cf]);
      }
    }
  };

  if (has_h) {
    bf16x8 aA[2][2], aB[2][2];
    STAGE(0, 0);
    LOADA(aA, 0);
    #pragma unroll
    for (int kt = 0; kt < 8; kt += 2) {
      if (kt + 1 < 8) {
        STAGE(1, kt + 1); LOADA(aB, kt + 1);
        WAIT_BAR(12);        // buf0 ready; buf1 stage + aB (12) in flight
      } else {
        WAIT_BAR(0);
      }
      COMPUTE(0, aA);
      LGKM_BAR;              // all waves done reading buf0
      if (kt + 2 < 8) {
        STAGE(0, kt + 2); LOADA(aA, kt + 2);
        WAIT_BAR(12);
      } else {
        WAIT_BAR(0);
      }
      COMPUTE(1, aB);
      LGKM_BAR;
    }
  }

  const int j = j0 + (lane & 15);
  const float woj = final_step ? Wo[j] : 0.0f;
  #pragma unroll
  for (int r = 0; r < 4; ++r) {
    int b = brow0 + (lane >> 4) * 4 + r;
    float4 gv = *(const float4*)&gx[((size_t)b * TT + t) * 2048 + (size_t)j * 4];
    float gi = acc[0][r] + gv.x;
    float gc = acc[1][r] + gv.y;
    float gf = acc[2][r] + gv.z;
    float go = acc[3][r] + gv.w;
    float cp = has_h ? c_in[(size_t)b * HH + j] : 0.0f;
    float cn = cp * sigm(gf + 1.0f) + sigm(gi) * tanhf(gc);
    float hn = sigm(go) * tanhf(cn);
    if (!final_step) {
      c_out[(size_t)b * HH + j] = cn;
      bf16_t hh = (bf16_t)hn;
      hhi_out[(size_t)b * HH + j] = hh;
      hlo_out[(size_t)b * HH + j] = (bf16_t)(hn - (float)hh);
    } else {
      // fused output projection: reduce hn*Wo[j] over the 16 j-lanes of this group
      float part = hn * woj;
      #pragma unroll
      for (int m = 1; m < 16; m <<= 1) part += __shfl_xor(part, m);
      if ((lane & 15) == 0)
        atomicAdd(&out[b], part + ((j0 == 0) ? bo[0] : 0.0f));
    }
  }
}

extern "C" void kernel_launch(void* const* d_in, const int* in_sizes, int n_in,
                              void* d_out, int out_size, void* d_ws, size_t ws_size,
                              hipStream_t stream) {
  const float* x  = (const float*)d_in[0];
  const float* Wd = (const float*)d_in[1];
  const float* Wc = (const float*)d_in[2];
  const float* bc = (const float*)d_in[3];
  const float* Wo = (const float*)d_in[4];
  const float* bo = (const float*)d_in[5];
  float* out = (float*)d_out;

  char* wsb = (char*)d_ws;
  size_t off = 0;
  auto alloc = [&](size_t bytes) -> void* {
    void* p = wsb + off;
    off = (off + bytes + 255) & ~(size_t)255;
    return p;
  };
  bf16_t* WdThi = (bf16_t*)alloc((size_t)128 * KPD * 2);
  bf16_t* WdTlo = (bf16_t*)alloc((size_t)128 * KPD * 2);
  bf16_t* WxThi = (bf16_t*)alloc((size_t)2048 * 128 * 2);
  bf16_t* WxTlo = (bf16_t*)alloc((size_t)2048 * 128 * 2);
  bf16_t* WhThi = (bf16_t*)alloc((size_t)2048 * 512 * 2);
  bf16_t* WhTlo = (bf16_t*)alloc((size_t)2048 * 512 * 2);
  float*  wN    = (float*)alloc(2048 * 4);
  float*  xa    = (float*)alloc((size_t)MROW * 128 * 4);
  float*  gx    = (float*)alloc((size_t)MROW * 2048 * 4);  // 64MB; front 32MB doubles as parts
  float*  parts = gx;                                      // parts (8 splits) dead after kRed
  bf16_t* h0hi = (bf16_t*)alloc((size_t)NB * HH * 2);
  bf16_t* h0lo = (bf16_t*)alloc((size_t)NB * HH * 2);
  bf16_t* h1hi = (bf16_t*)alloc((size_t)NB * HH * 2);
  bf16_t* h1lo = (bf16_t*)alloc((size_t)NB * HH * 2);
  float*  c0   = (float*)alloc((size_t)NB * HH * 4);
  float*  c1   = (float*)alloc((size_t)NB * HH * 4);
  bf16_t* hhi[2] = {h0hi, h1hi};
  bf16_t* hlo[2] = {h0lo, h1lo};
  float*  cb[2]  = {c0, c1};

  hipMemsetAsync(out, 0, (size_t)out_size * 4, stream);  // final step atomicAdds into out
  kPrep<<<336, 256, 0, stream>>>(Wd, Wc, WdThi, WdTlo, WxThi, WxTlo, wN, WhThi, WhTlo);
  kA_mfma<<<dim3(64, KSPLIT), 256, 0, stream>>>(x, WdThi, WdTlo, parts);
  kRed<<<1024, 256, 0, stream>>>(parts, xa);
  kGx<<<dim3(64, 16), 512, 0, stream>>>(xa, x, WxThi, WxTlo, wN, bc, gx);
  for (int t = 0; t < TT; ++t) {
    kStepH<<<dim3(32, 16), 128, 0, stream>>>(hhi[t & 1], hlo[t & 1], WhThi, WhTlo,
        gx, cb[t & 1], hhi[(t + 1) & 1], hlo[(t + 1) & 1], cb[(t + 1) & 1],
        Wo, bo, out, t, (t == 0) ? 0 : 1, (t == TT - 1) ? 1 : 0);
  }
}

// Round 19
// 397.624 us; speedup vs baseline: 1.7141x; 1.7141x over previous
//
#include <hip/hip_runtime.h>
#include <cmath>

#define TID ((int)threadIdx.x)

typedef __bf16 bf16_t;
typedef bf16_t bf16x8 __attribute__((ext_vector_type(8)));
typedef float floatx4 __attribute__((ext_vector_type(4)));

#define MFMA(a, b, c) __builtin_amdgcn_mfma_f32_16x16x32_bf16(a, b, c, 0, 0, 0)
// barrier #1 of a phase: buf ready (drain all but the N just-issued prefetch loads)
#define WAIT_BAR(N)  do { asm volatile("s_waitcnt vmcnt(" #N ")" ::: "memory"); \
                          __builtin_amdgcn_s_barrier(); \
                          __builtin_amdgcn_sched_barrier(0); } while (0)
// barrier #2 of a phase: this wave's ds_reads complete -> after barrier, buf may be overwritten
#define LGKM_BAR     do { asm volatile("s_waitcnt lgkmcnt(0)" ::: "memory"); \
                          __builtin_amdgcn_s_barrier(); \
                          __builtin_amdgcn_sched_barrier(0); } while (0)

constexpr int N_IN = 10000;
constexpr int XP   = 10001;   // x row pitch
constexpr int KPD  = 10240;   // padded K for W_down^T
constexpr int HH   = 512;
constexpr int TT   = 16;
constexpr int NB   = 512;
constexpr int MROW = 8192;    // NB*TT
constexpr int KSPLIT = 16;    // KT_A=10: deeper unroll (KSPLIT=8/KT_A=20) spills VGPRs (R18)
constexpr int KCHUNK = 640;   // KPD/KSPLIT
constexpr int KT_A = 10;      // KCHUNK/64

__device__ __forceinline__ float sigm(float x) { return 1.0f / (1.0f + expf(-x)); }

__device__ __forceinline__ void gload16(const void* g, void* lds) {
  __builtin_amdgcn_global_load_lds(
      (const __attribute__((address_space(1))) unsigned int*)g,
      (__attribute__((address_space(3))) unsigned int*)lds, 16, 0, 0);
}

// ---------- fused prep: blocks 0-159 -> W_down split/transpose; 160-335 -> W_cell split
__global__ __launch_bounds__(256)
void kPrep(const float* __restrict__ Wd, const float* __restrict__ Wc,
           bf16_t* __restrict__ Whi, bf16_t* __restrict__ Wlo,
           bf16_t* __restrict__ Wxh, bf16_t* __restrict__ Wxl,
           float* __restrict__ wN, bf16_t* __restrict__ Whh, bf16_t* __restrict__ Whl) {
  __shared__ float Ts[64][133];
  const int lane = TID & 63, w = TID >> 6;
  if (blockIdx.x < 160) {
    // ---- W_down (10000x128) -> WdT hi/lo bf16 [128][10240]
    const int k0 = blockIdx.x * 64;
    #pragma unroll
    for (int i = 0; i < 32; ++i) {
      int f = TID + 256 * i;
      int kk = f >> 7, c = f & 127;
      int k = k0 + kk;
      Ts[kk][c] = (k < N_IN) ? Wd[(size_t)k * 128 + c] : 0.0f;
    }
    __syncthreads();
    for (int pass = 0; pass < 32; ++pass) {
      int c = pass * 4 + w;
      float v = Ts[lane][c];
      bf16_t hi = (bf16_t)v;
      bf16_t lo = (bf16_t)(v - (float)hi);
      Whi[(size_t)c * KPD + k0 + lane] = hi;
      Wlo[(size_t)c * KPD + k0 + lane] = lo;
    }
  } else {
    // ---- W_cell (641x2048) -> WxT[2048][128], wN[2048], WhT[2048][512] (hi/lo)
    const int id = blockIdx.x - 160;           // 0..175 = 11 k-tiles x 16 c-tiles
    const int k0 = (id % 11) * 64;
    const int c0 = (id / 11) * 128;
    #pragma unroll
    for (int i = 0; i < 32; ++i) {
      int f = TID + 256 * i;
      int kk = f >> 7, cc = f & 127;
      int k = k0 + kk;
      Ts[kk][cc] = (k < 641) ? Wc[(size_t)k * 2048 + c0 + cc] : 0.0f;
    }
    __syncthreads();
    const int k = k0 + lane;
    for (int pass = 0; pass < 32; ++pass) {
      int cc = pass * 4 + w;
      int c = c0 + cc;
      float v = Ts[lane][cc];
      bf16_t hi = (bf16_t)v;
      bf16_t lo = (bf16_t)(v - (float)hi);
      if (k < 128) {
        Wxh[(size_t)c * 128 + k] = hi;
        Wxl[(size_t)c * 128 + k] = lo;
      } else if (k == 128) {
        wN[c] = v;
      } else if (k < 641) {
        Whh[(size_t)c * 512 + (k - 129)] = hi;
        Whl[(size_t)c * 512 + (k - 129)] = lo;
      }
    }
  }
}

// ---------- kernel A: parts[s] = x @ W_down chunk, bf16 3-pass MFMA (kt=64, 64KB dbuf)
// 2-ahead x prefetch (3 reg buffers) + 1-ahead LDS stage, counted-vmcnt two-barrier phases.
// grid (64 row-tiles, 16 splits), 256 thr / 4 waves; wave 32 rows x 128 cols
__global__ __launch_bounds__(256, 2)
void kA_mfma(const float* __restrict__ x, const bf16_t* __restrict__ Whi,
             const bf16_t* __restrict__ Wlo, float* __restrict__ parts) {
  // chunk L = arr*1024 + col*8 + g (16B each); linear dest, pre-swizzled source
  __shared__ __align__(16) bf16_t Bt[2][2048 * 8];
  const int lane = TID & 63, w = TID >> 6;
  const int row0 = blockIdx.x * 128 + w * 32;
  const int kbase = blockIdx.y * KCHUNK;
  floatx4 acc[2][8] = {};

  auto STAGE = [&](int buf, int kt) {
    const int k0 = kbase + kt * 64;
    #pragma unroll
    for (int i = 0; i < 8; ++i) {
      int L = i * 256 + TID;
      int arr = L >> 10, col = (L >> 3) & 127, g = L & 7;
      int gs = g ^ (col & 7);
      const bf16_t* src = (arr ? Wlo : Whi) + (size_t)col * KPD + k0 + gs * 8;
      gload16(src, &Bt[buf][(size_t)L * 8]);
    }
  };
  // branchless: loads ALWAYS issued (clamped in-bounds addr), zeros selected after.
  auto LOADX = [&](float4 (&xb)[2][2][2], int kt) {
    const int k0 = kbase + kt * 64;
    #pragma unroll
    for (int rf = 0; rf < 2; ++rf) {
      const float* xp = x + (size_t)(row0 + rf * 16 + (lane & 15)) * XP;
      #pragma unroll
      for (int h = 0; h < 2; ++h) {
        int kk0 = k0 + h * 32 + (lane >> 4) * 8;
        int kc = (kk0 < N_IN) ? kk0 : (N_IN - 8);   // always valid, 8 floats in-bounds
        float4 v0 = *(const float4*)(xp + kc);
        float4 v1 = *(const float4*)(xp + kc + 4);
        if (kk0 >= N_IN) {
          v0 = make_float4(0.f, 0.f, 0.f, 0.f);
          v1 = make_float4(0.f, 0.f, 0.f, 0.f);
        }
        xb[rf][h][0] = v0;
        xb[rf][h][1] = v1;
      }
    }
  };
  auto COMPUTE = [&](int buf, const float4 (&xb)[2][2][2]) {
    #pragma unroll
    for (int h = 0; h < 2; ++h) {
      const int p = h * 4 + (lane >> 4);
      bf16x8 ahi[2], alo[2];
      #pragma unroll
      for (int rf = 0; rf < 2; ++rf) {
        float vv[8] = {xb[rf][h][0].x, xb[rf][h][0].y, xb[rf][h][0].z, xb[rf][h][0].w,
                       xb[rf][h][1].x, xb[rf][h][1].y, xb[rf][h][1].z, xb[rf][h][1].w};
        #pragma unroll
        for (int e = 0; e < 8; ++e) {
          bf16_t hi = (bf16_t)vv[e];
          ahi[rf][e] = hi;
          alo[rf][e] = (bf16_t)(vv[e] - (float)hi);
        }
      }
      #pragma unroll
      for (int cf = 0; cf < 8; ++cf) {
        const int col = cf * 16 + (lane & 15);
        const int g = p ^ (col & 7);
        bf16x8 bhi = *(const bf16x8*)&Bt[buf][(col * 8 + g) * 8];
        bf16x8 blo = *(const bf16x8*)&Bt[buf][(1024 + col * 8 + g) * 8];
        #pragma unroll
        for (int rf = 0; rf < 2; ++rf) {
          acc[rf][cf] = MFMA(ahi[rf], bhi, acc[rf][cf]);
          acc[rf][cf] = MFMA(ahi[rf], blo, acc[rf][cf]);
          acc[rf][cf] = MFMA(alo[rf], bhi, acc[rf][cf]);
        }
      }
    }
  };

  float4 xb0[2][2][2], xb1[2][2][2], xb2[2][2][2];
  STAGE(0, 0); LOADX(xb0, 0);
  STAGE(1, 1); LOADX(xb1, 1);
  LOADX(xb2, 2);
  #pragma unroll
  for (int kt = 0; kt < KT_A; ++kt) {
    if (kt <= KT_A - 3)      WAIT_BAR(24);
    else if (kt == KT_A - 2) WAIT_BAR(16);
    else                     WAIT_BAR(0);
    if (kt % 3 == 0)      COMPUTE(kt & 1, xb0);
    else if (kt % 3 == 1) COMPUTE(kt & 1, xb1);
    else                  COMPUTE(kt & 1, xb2);
    LGKM_BAR;
    if (kt + 2 < KT_A) STAGE(kt & 1, kt + 2);
    if (kt + 3 < KT_A) {
      if ((kt + 3) % 3 == 0)      LOADX(xb0, kt + 3);
      else if ((kt + 3) % 3 == 1) LOADX(xb1, kt + 3);
      else                        LOADX(xb2, kt + 3);
    }
  }

  float* dst = parts + (size_t)blockIdx.y * MROW * 128;
  #pragma unroll
  for (int rf = 0; rf < 2; ++rf)
    #pragma unroll
    for (int cf = 0; cf < 8; ++cf)
      #pragma unroll
      for (int r = 0; r < 4; ++r) {
        int row = row0 + rf * 16 + (lane >> 4) * 4 + r;
        int col = cf * 16 + (lane & 15);
        dst[(size_t)row * 128 + col] = acc[rf][cf][r];
      }
}

// ---------- reduce partials -> xa [8192][128] (row = b*16+t)
__global__ __launch_bounds__(256)
void kRed(const float* __restrict__ parts, float* __restrict__ xa) {
  size_t i4 = ((size_t)blockIdx.x * 256 + TID) * 4;
  float4 v = make_float4(0.f, 0.f, 0.f, 0.f);
  #pragma unroll
  for (int s = 0; s < KSPLIT; ++s) {
    float4 p = *(const float4*)&parts[(size_t)s * MROW * 128 + i4];
    v.x += p.x; v.y += p.y; v.z += p.z; v.w += p.w;
  }
  *(float4*)&xa[i4] = v;
}

// ---------- gx = xa @ Wx + bc + x[:,N]*wN, layout gx[row][j*4+g], row = b*16+t
// grid (64 row-tiles, 16 col-tiles), 512 thr / 8 waves (4 row x 2 col), wave 32x64
__global__ __launch_bounds__(512, 2)
void kGx(const float* __restrict__ xa, const float* __restrict__ x,
         const bf16_t* __restrict__ Wxh, const bf16_t* __restrict__ Wxl,
         const float* __restrict__ wN, const float* __restrict__ bc,
         float* __restrict__ gx) {
  __shared__ __align__(16) bf16_t Bt[4096 * 8];
  const int lane = TID & 63, w = TID >> 6;
  const int wr = w & 3, wc = w >> 2;
  const int rowbase = blockIdx.x * 128 + wr * 32;
  const int JB = blockIdx.y * 32;
  floatx4 acc[2][4] = {};

  #pragma unroll
  for (int i = 0; i < 8; ++i) {
    int L = i * 512 + TID;
    int arr = L >> 11, ce = (L >> 4) & 127, g = L & 15;
    int gs = g ^ (ce & 15);
    int c_src = (ce & 3) * 512 + JB + (ce >> 2);
    const bf16_t* src = (arr ? Wxl : Wxh) + (size_t)c_src * 128 + gs * 8;
    gload16(src, &Bt[(size_t)L * 8]);
  }
  float4 xb[2][2][2][2];  // [kt][rf][h][half]
  #pragma unroll
  for (int kt = 0; kt < 2; ++kt)
    #pragma unroll
    for (int rf = 0; rf < 2; ++rf) {
      const float* ap = xa + (size_t)(rowbase + rf * 16 + (lane & 15)) * 128;
      #pragma unroll
      for (int h = 0; h < 2; ++h) {
        int kk0 = kt * 64 + h * 32 + (lane >> 4) * 8;
        xb[kt][rf][h][0] = *(const float4*)(ap + kk0);
        xb[kt][rf][h][1] = *(const float4*)(ap + kk0 + 4);
      }
    }
  __syncthreads();
  #pragma unroll
  for (int kt = 0; kt < 2; ++kt) {
    #pragma unroll
    for (int h = 0; h < 2; ++h) {
      const int p = kt * 8 + h * 4 + (lane >> 4);
      bf16x8 ahi[2], alo[2];
      #pragma unroll
      for (int rf = 0; rf < 2; ++rf) {
        float vv[8] = {xb[kt][rf][h][0].x, xb[kt][rf][h][0].y, xb[kt][rf][h][0].z, xb[kt][rf][h][0].w,
                       xb[kt][rf][h][1].x, xb[kt][rf][h][1].y, xb[kt][rf][h][1].z, xb[kt][rf][h][1].w};
        #pragma unroll
        for (int e = 0; e < 8; ++e) {
          bf16_t hi = (bf16_t)vv[e];
          ahi[rf][e] = hi;
          alo[rf][e] = (bf16_t)(vv[e] - (float)hi);
        }
      }
      #pragma unroll
      for (int cf = 0; cf < 4; ++cf) {
        const int ce = wc * 64 + cf * 16 + (lane & 15);
        const int g = p ^ (ce & 15);
        bf16x8 bhi = *(const bf16x8*)&Bt[(ce * 16 + g) * 8];
        bf16x8 blo = *(const bf16x8*)&Bt[(2048 + ce * 16 + g) * 8];
        #pragma unroll
        for (int rf = 0; rf < 2; ++rf) {
          acc[rf][cf] = MFMA(ahi[rf], bhi, acc[rf][cf]);
          acc[rf][cf] = MFMA(ahi[rf], blo, acc[rf][cf]);
          acc[rf][cf] = MFMA(alo[rf], bhi, acc[rf][cf]);
        }
      }
    }
  }
  #pragma unroll
  for (int rf = 0; rf < 2; ++rf)
    #pragma unroll
    for (int cf = 0; cf < 4; ++cf) {
      const int ce = wc * 64 + cf * 16 + (lane & 15);
      const int n = blockIdx.y * 128 + ce;
      const int c_src = (ce & 3) * 512 + JB + (ce >> 2);
      const float bias = bc[c_src];
      const float wn = wN[c_src];
      #pragma unroll
      for (int r = 0; r < 4; ++r) {
        int row = rowbase + rf * 16 + (lane >> 4) * 4 + r;
        float xwv = x[(size_t)row * XP + N_IN];
        gx[(size_t)row * 2048 + n] = acc[rf][cf][r] + bias + xwv * wn;
      }
    }
}

// ---------- one LSTM step: gates = h @ WhT + gx; pointwise; h out as bf16 hi/lo.
// When final: skip h/c stores, fused output projection via 16-lane reduce + atomicAdd.
// grid (32,16), 128 thr / 2 waves; two-barrier counted-vmcnt phases (12 in-flight).
__global__ __launch_bounds__(128, 2)
void kStepH(const bf16_t* __restrict__ hhi_in, const bf16_t* __restrict__ hlo_in,
            const bf16_t* __restrict__ Whh, const bf16_t* __restrict__ Whl,
            const float* __restrict__ gx, const float* __restrict__ c_in,
            bf16_t* __restrict__ hhi_out, bf16_t* __restrict__ hlo_out,
            float* __restrict__ c_out, const float* __restrict__ Wo,
            const float* __restrict__ bo, float* __restrict__ out,
            int t, int has_h, int final_step) {
  __shared__ __align__(16) bf16_t Bt[2][1024 * 8];  // L = arr*512 + ce*8 + g
  const int lane = TID & 63, w = TID >> 6;
  const int j0 = blockIdx.x * 16;
  const int brow0 = blockIdx.y * 32 + w * 16;
  floatx4 acc[4] = {};

  auto STAGE = [&](int buf, int kt) {
    const int k0 = kt * 64;
    #pragma unroll
    for (int i = 0; i < 8; ++i) {
      int L = i * 128 + TID;
      int arr = L >> 9, ce = (L >> 3) & 63, g = L & 7;
      int gs = g ^ (ce & 7);
      int c_src = (ce >> 4) * 512 + j0 + (ce & 15);
      const bf16_t* src = (arr ? Whl : Whh) + (size_t)c_src * 512 + k0 + gs * 8;
      gload16(src, &Bt[buf][(size_t)L * 8]);
    }
  };
  auto LOADA = [&](bf16x8 (&ar)[2][2], int kt) {
    const int b = brow0 + (lane & 15);
    #pragma unroll
    for (int h = 0; h < 2; ++h) {
      const int kk0 = kt * 64 + h * 32 + (lane >> 4) * 8;
      ar[h][0] = *(const bf16x8*)&hhi_in[(size_t)b * HH + kk0];
      ar[h][1] = *(const bf16x8*)&hlo_in[(size_t)b * HH + kk0];
    }
  };
  auto COMPUTE = [&](int buf, const bf16x8 (&ar)[2][2]) {
    #pragma unroll
    for (int h = 0; h < 2; ++h) {
      const int p = h * 4 + (lane >> 4);
      #pragma unroll
      for (int cf = 0; cf < 4; ++cf) {
        const int ce = cf * 16 + (lane & 15);
        const int g = p ^ (ce & 7);
        bf16x8 bhi = *(const bf16x8*)&Bt[buf][(ce * 8 + g) * 8];
        bf16x8 blo = *(const bf16x8*)&Bt[buf][(512 + ce * 8 + g) * 8];
        acc[cf] = MFMA(ar[h][0], bhi, acc[cf]);
        acc[cf] = MFMA(ar[h][0], blo, acc[cf]);
        acc[cf] = MFMA(ar[h][1], bhi, acc[cf]);
      }
    }
  };

  if (has_h) {
    bf16x8 aA[2][2], aB[2][2];
    STAGE(0, 0);
    LOADA(aA, 0);
    #pragma unroll
    for (int kt = 0; kt < 8; kt += 2) {
      if (kt + 1 < 8) {
        STAGE(1, kt + 1); LOADA(aB, kt + 1);
        WAIT_BAR(12);        // buf0 ready; buf1 stage + aB (12) in flight
      } else {
        WAIT_BAR(0);
      }
      COMPUTE(0, aA);
      LGKM_BAR;              // all waves done reading buf0
      if (kt + 2 < 8) {
        STAGE(0, kt + 2); LOADA(aA, kt + 2);
        WAIT_BAR(12);
      } else {
        WAIT_BAR(0);
      }
      COMPUTE(1, aB);
      LGKM_BAR;
    }
  }

  const int j = j0 + (lane & 15);
  const float woj = final_step ? Wo[j] : 0.0f;
  #pragma unroll
  for (int r = 0; r < 4; ++r) {
    int b = brow0 + (lane >> 4) * 4 + r;
    float4 gv = *(const float4*)&gx[((size_t)b * TT + t) * 2048 + (size_t)j * 4];
    float gi = acc[0][r] + gv.x;
    float gc = acc[1][r] + gv.y;
    float gf = acc[2][r] + gv.z;
    float go = acc[3][r] + gv.w;
    float cp = has_h ? c_in[(size_t)b * HH + j] : 0.0f;
    float cn = cp * sigm(gf + 1.0f) + sigm(gi) * tanhf(gc);
    float hn = sigm(go) * tanhf(cn);
    if (!final_step) {
      c_out[(size_t)b * HH + j] = cn;
      bf16_t hh = (bf16_t)hn;
      hhi_out[(size_t)b * HH + j] = hh;
      hlo_out[(size_t)b * HH + j] = (bf16_t)(hn - (float)hh);
    } else {
      // fused output projection: reduce hn*Wo[j] over the 16 j-lanes of this group
      float part = hn * woj;
      #pragma unroll
      for (int m = 1; m < 16; m <<= 1) part += __shfl_xor(part, m);
      if ((lane & 15) == 0)
        atomicAdd(&out[b], part + ((j0 == 0) ? bo[0] : 0.0f));
    }
  }
}

extern "C" void kernel_launch(void* const* d_in, const int* in_sizes, int n_in,
                              void* d_out, int out_size, void* d_ws, size_t ws_size,
                              hipStream_t stream) {
  const float* x  = (const float*)d_in[0];
  const float* Wd = (const float*)d_in[1];
  const float* Wc = (const float*)d_in[2];
  const float* bc = (const float*)d_in[3];
  const float* Wo = (const float*)d_in[4];
  const float* bo = (const float*)d_in[5];
  float* out = (float*)d_out;

  char* wsb = (char*)d_ws;
  size_t off = 0;
  auto alloc = [&](size_t bytes) -> void* {
    void* p = wsb + off;
    off = (off + bytes + 255) & ~(size_t)255;
    return p;
  };
  bf16_t* WdThi = (bf16_t*)alloc((size_t)128 * KPD * 2);
  bf16_t* WdTlo = (bf16_t*)alloc((size_t)128 * KPD * 2);
  bf16_t* WxThi = (bf16_t*)alloc((size_t)2048 * 128 * 2);
  bf16_t* WxTlo = (bf16_t*)alloc((size_t)2048 * 128 * 2);
  bf16_t* WhThi = (bf16_t*)alloc((size_t)2048 * 512 * 2);
  bf16_t* WhTlo = (bf16_t*)alloc((size_t)2048 * 512 * 2);
  float*  wN    = (float*)alloc(2048 * 4);
  float*  xa    = (float*)alloc((size_t)MROW * 128 * 4);
  float*  parts = (float*)alloc((size_t)KSPLIT * MROW * 128 * 4);  // 64MB, reused as gx
  float*  gx    = parts;                                           // alias: parts dead after kRed
  bf16_t* h0hi = (bf16_t*)alloc((size_t)NB * HH * 2);
  bf16_t* h0lo = (bf16_t*)alloc((size_t)NB * HH * 2);
  bf16_t* h1hi = (bf16_t*)alloc((size_t)NB * HH * 2);
  bf16_t* h1lo = (bf16_t*)alloc((size_t)NB * HH * 2);
  float*  c0   = (float*)alloc((size_t)NB * HH * 4);
  float*  c1   = (float*)alloc((size_t)NB * HH * 4);
  bf16_t* hhi[2] = {h0hi, h1hi};
  bf16_t* hlo[2] = {h0lo, h1lo};
  float*  cb[2]  = {c0, c1};

  hipMemsetAsync(out, 0, (size_t)out_size * 4, stream);  // final step atomicAdds into out
  kPrep<<<336, 256, 0, stream>>>(Wd, Wc, WdThi, WdTlo, WxThi, WxTlo, wN, WhThi, WhTlo);
  kA_mfma<<<dim3(64, KSPLIT), 256, 0, stream>>>(x, WdThi, WdTlo, parts);
  kRed<<<1024, 256, 0, stream>>>(parts, xa);
  kGx<<<dim3(64, 16), 512, 0, stream>>>(xa, x, WxThi, WxTlo, wN, bc, gx);
  for (int t = 0; t < TT; ++t) {
    kStepH<<<dim3(32, 16), 128, 0, stream>>>(hhi[t & 1], hlo[t & 1], WhThi, WhTlo,
        gx, cb[t & 1], hhi[(t + 1) & 1], hlo[(t + 1) & 1], cb[(t + 1) & 1],
        Wo, bo, out, t, (t == 0) ? 0 : 1, (t == TT - 1) ? 1 : 0);
  }
}